// Round 2
// baseline (234.812 us; speedup 1.0000x reference)
//
#include <hip/hip_runtime.h>

// CSR-gather pipeline (no float atomics), 9 stream nodes:
//   memset(deg) ; deg_cast (deg hist + x->fp16) ; scan_partial ; scan_final ;
//   fill_a ; fill_b (bucketed CSR) ; gather32 ; h1tab (fused h1 + W1-split tables,
//   LDS layout round-trip) ; edge_mlp (fp16 MFMA + fused GCN2, node-pipelined) ;
//   gcn2_gather
// R2: keep R1's edge_mlp software pipeline (next-node ptr/atab/first-csr prefetch)
//     and DPP row_ror rotate-add trees (xor-1/2/4/8 inside 16-lane rows, pure VALU);
//     REVERT the hand-asm permlane16/32 swaps (prime suspect for R1's absmax fail)
//     back to known-good __shfl_xor for the 16/32 exchanges.

typedef __attribute__((ext_vector_type(8))) short short8;
typedef __attribute__((ext_vector_type(4))) float f32x4;
typedef __attribute__((ext_vector_type(8))) _Float16 f16x8;
typedef __attribute__((ext_vector_type(4))) _Float16 f16x4;
typedef __attribute__((ext_vector_type(2))) _Float16 f16x2;

#define SCAN_CHUNK 2048   // elements per scan block (256 thr x 8)
#define FILL_CH 4096      // edges per phase-A block (256 thr x 16)

__device__ __forceinline__ unsigned short f2bf(float x) {   // RNE f32->bf16 (cold paths only)
    unsigned int u = __float_as_uint(x);
    return (unsigned short)((u + 0x7FFFu + ((u >> 16) & 1u)) >> 16);
}
__device__ __forceinline__ float bf2f(unsigned short h) {
    return __uint_as_float(((unsigned int)h) << 16);
}
// cheap truncation split: u ~= hi + lo with |err| ~ 2^-16 |u|
__device__ __forceinline__ void splitT(float u, short& hi, short& lo) {
    unsigned int ub = __float_as_uint(u);
    hi = (short)(ub >> 16);
    float r = u - __uint_as_float(ub & 0xFFFF0000u);
    lo = (short)(__float_as_uint(r) >> 16);
}
__device__ __forceinline__ f16x8 relu8(f16x8 v) {
    f16x8 z = {0, 0, 0, 0, 0, 0, 0, 0};
#if __has_builtin(__builtin_elementwise_max)
    return __builtin_elementwise_max(v, z);
#else
    f16x8 o;
#pragma unroll
    for (int j = 0; j < 8; ++j) o[j] = v[j] > (_Float16)0 ? v[j] : (_Float16)0;
    return o;
#endif
}

// rotate-add within a 16-lane row (DPP row_ror:N); rotation tree 1,2,4,8 == full
// 16-lane sum in every lane. Pure VALU, no lgkm wait. (row_ror = 0x120+N.)
#define ROR_ADD(s, CTRL)                                                         \
    s += __int_as_float(__builtin_amdgcn_update_dpp(                             \
        0, __float_as_int(s), (CTRL), 0xf, 0xf, false))
// xor-8 within a 16-lane row is row_ror:8 (flips bit 3 only)
#define ROR8_ADD(s) ROR_ADD(s, 0x128)

// fused: degree histogram + x -> fp16 cast
__global__ void k_deg_cast(const int* __restrict__ col, int* __restrict__ deg,
                           const float4* __restrict__ x4, f16x4* __restrict__ xh4,
                           int E, int m4) {
    int e = blockIdx.x * blockDim.x + threadIdx.x;
    if (e < m4) {
        float4 v = x4[e];
        f16x4 o;
        o[0] = (_Float16)v.x; o[1] = (_Float16)v.y;
        o[2] = (_Float16)v.z; o[3] = (_Float16)v.w;
        xh4[e] = o;
    }
    if (e < E) atomicAdd(&deg[col[e]], 1);
}

__global__ __launch_bounds__(256) void k_scan_partial(const int* __restrict__ deg,
                                                      int* __restrict__ part, int n) {
    __shared__ int wtot[4];
    int tid = threadIdx.x;
    int base = blockIdx.x * SCAN_CHUNK + tid * 8;
    int s = 0;
#pragma unroll
    for (int i = 0; i < 8; ++i) { int idx = base + i; if (idx < n) s += deg[idx]; }
    for (int off = 1; off < 64; off <<= 1) s += __shfl_xor(s, off);
    if ((tid & 63) == 0) wtot[tid >> 6] = s;
    __syncthreads();
    if (tid == 0) part[blockIdx.x] = wtot[0] + wtot[1] + wtot[2] + wtot[3];
}

// merged: per-block offset from partials (wave 0, in-register) + block-local
// exclusive scan + ptr + bcur + dinv
__global__ __launch_bounds__(256) void k_scan_final(const int* __restrict__ deg,
                                                    const int* __restrict__ part,
                                                    int* __restrict__ ptr,
                                                    int* __restrict__ bcur,
                                                    float* __restrict__ dinv,
                                                    int n, int nb, int E) {
    __shared__ int wtot[4];
    __shared__ int offsS;
    int tid = threadIdx.x;
    int lane = tid & 63, wv = tid >> 6;
    if (wv == 0) {                          // re-scan <=64 partials, keep ours
        int p = (lane < nb) ? part[lane] : 0;
        int s = p;
        for (int off = 1; off < 64; off <<= 1) {
            int t = __shfl_up(s, off, 64);
            if (lane >= off) s += t;
        }
        if (lane == (int)blockIdx.x) offsS = s - p;   // exclusive
        if (blockIdx.x == 0 && lane == 0) ptr[n] = E;
    }
    int base = blockIdx.x * SCAN_CHUNK + tid * 8;
    int d[8];
    int t8 = 0;
#pragma unroll
    for (int i = 0; i < 8; ++i) {
        int idx = base + i;
        d[i] = (idx < n) ? deg[idx] : 0;
        t8 += d[i];
    }
    int s = t8;
    for (int off = 1; off < 64; off <<= 1) {
        int t = __shfl_up(s, off, 64);
        if (lane >= off) s += t;
    }
    if (lane == 63) wtot[wv] = s;
    __syncthreads();
    int wpre = 0;
    for (int w = 0; w < 4; ++w) if (w < wv) wpre += wtot[w];
    int run = offsS + wpre + (s - t8);
#pragma unroll
    for (int i = 0; i < 8; ++i) {
        int idx = base + i;
        if (idx < n) {
            ptr[idx] = run;
            if ((idx & 127) == 0) bcur[idx >> 7] = run;   // bucket staging base
            dinv[idx] = rsqrtf((float)(d[i] + 1));        // +1 self loop
            run += d[i];
        }
    }
}

// fill phase A: bucket edges (128 cols/bucket) into contiguous per-bucket runs
__global__ __launch_bounds__(256) void k_fill_a(const int* __restrict__ row,
                                                const int* __restrict__ col,
                                                int* __restrict__ bcur,
                                                int2* __restrict__ stage, int E, int nb) {
    __shared__ int cnt[512];
    __shared__ int base[512];
    int tid = threadIdx.x;
    int e0 = blockIdx.x * FILL_CH;
    for (int i = tid; i < nb; i += 256) cnt[i] = 0;
    __syncthreads();
    int r[16], c[16];
#pragma unroll
    for (int i = 0; i < 16; ++i) {
        int e = e0 + tid + i * 256;
        if (e < E) {
            r[i] = row[e]; c[i] = col[e];
            atomicAdd(&cnt[c[i] >> 7], 1);
        } else c[i] = -1;
    }
    __syncthreads();
    for (int i = tid; i < nb; i += 256)
        base[i] = cnt[i] ? atomicAdd(&bcur[i], cnt[i]) : 0;
    __syncthreads();
    for (int i = tid; i < nb; i += 256) cnt[i] = 0;
    __syncthreads();
#pragma unroll
    for (int i = 0; i < 16; ++i) {
        if (c[i] >= 0) {
            int b = c[i] >> 7;
            int lp = atomicAdd(&cnt[b], 1);
            stage[base[b] + lp] = make_int2(r[i], c[i]);
        }
    }
}

// fill phase B: one block per bucket; LDS cursors; csr writes stay in one L2
__global__ __launch_bounds__(256) void k_fill_b(const int* __restrict__ ptr,
                                                const int2* __restrict__ stage,
                                                int* __restrict__ csr, int n) {
    __shared__ int lcur[128];
    int b = blockIdx.x;
    int tid = threadIdx.x;
    int c0 = b << 7;
    for (int j = tid; j < 128; j += 256) {
        int idx = c0 + j; if (idx > n) idx = n;
        lcur[j] = ptr[idx];
    }
    __syncthreads();
    int start = ptr[c0];
    int endi = c0 + 128; if (endi > n) endi = n;
    int end = ptr[endi];
    for (int p = start + tid; p < end; p += 256) {
        int2 rc = stage[p];
        int pos = atomicAdd(&lcur[rc.y & 127], 1);
        csr[pos] = rc.x;
    }
}

// irregular gather (fp16 x): agg[v] = dv*(sum dinv[r]*xh[r]) + dv^2*x[v]
// 8 edge slots x 8 lanes x half4; one-ahead index prefetch; fp32 accumulate
__global__ __launch_bounds__(256) void k_gather32(
        const int* __restrict__ ptr, const int* __restrict__ csr_row,
        const float* __restrict__ x, const _Float16* __restrict__ xh,
        const float* __restrict__ dinv, float* __restrict__ agg, int n) {
    int wid = blockIdx.x * 4 + (threadIdx.x >> 6);
    if (wid >= n) return;
    int lane = threadIdx.x & 63;
    int f4 = lane & 7, slot = lane >> 3;
    int v = wid;
    int start = ptr[v], end = ptr[v + 1];
    const f16x4* xh4 = (const f16x4*)xh;
    float sx = 0.f, sy = 0.f, sz = 0.f, sw = 0.f;
    int p = start + slot;
    int r = (p < end) ? csr_row[p] : 0;
    while (p < end) {
        int rcur = r;
        int pn = p + 8;
        if (pn < end) r = csr_row[pn];
        float dr = dinv[rcur];
        f16x4 xv = xh4[(size_t)rcur * 8 + f4];
        sx = fmaf(dr, (float)xv[0], sx);
        sy = fmaf(dr, (float)xv[1], sy);
        sz = fmaf(dr, (float)xv[2], sz);
        sw = fmaf(dr, (float)xv[3], sw);
        p = pn;
    }
    // xor-8 via DPP (pure VALU); xor-16/32 via shfl (known-good)
    ROR8_ADD(sx); ROR8_ADD(sy); ROR8_ADD(sz); ROR8_ADD(sw);
#pragma unroll
    for (int off = 16; off < 64; off <<= 1) {
        sx += __shfl_xor(sx, off); sy += __shfl_xor(sy, off);
        sz += __shfl_xor(sz, off); sw += __shfl_xor(sw, off);
    }
    if (slot == 0) {
        float dv = dinv[v], d2 = dv * dv;
        float4 xv = ((const float4*)x)[(size_t)v * 8 + f4];   // self term fp32
        float4 o;
        o.x = dv * sx + d2 * xv.x;
        o.y = dv * sy + d2 * xv.y;
        o.z = dv * sz + d2 * xv.z;
        o.w = dv * sw + d2 * xv.w;
        ((float4*)agg)[(size_t)v * 8 + f4] = o;
    }
}

// FUSED dense MFMA: h1 = tanh(agg @ Wg1 + gb)  then  atab = h1@(W1a-W1b)+b1 ;
// btab = h1@W1b (fp16 out). h1 never leaves the CU: C/D -> A layout transform
// via wave-private LDS tile (16 x 66, pad keeps <=2-way bank aliasing).
__global__ __launch_bounds__(256, 1) void k_h1tab(
        const float* __restrict__ agg, const float* __restrict__ gw,
        const float* __restrict__ gb, const float* __restrict__ w1,
        const float* __restrict__ b1,
        _Float16* __restrict__ atab, _Float16* __restrict__ btab, int ntiles) {
    __shared__ float tileS[4][16 * 66];
    int lane = threadIdx.x & 63;
    int wv = threadIdx.x >> 6;
    int n16 = lane & 15, q = lane >> 4;
    float* T = tileS[wv];

    // Wg1 frags (bf16 3-term) + gb
    short8 gh[4], gl[4];
    float gbias[4];
#pragma unroll
    for (int t = 0; t < 4; ++t) {
        gbias[t] = gb[t * 16 + n16];
        short8 hh, ll;
#pragma unroll
        for (int j = 0; j < 8; ++j) {
            float w = gw[(q * 8 + j) * 64 + t * 16 + n16];
            unsigned short wh = f2bf(w);
            hh[j] = (short)wh;
            ll[j] = (short)f2bf(w - bf2f(wh));
        }
        gh[t] = hh; gl[t] = ll;
    }
    // W1 frags (bf16 3-term, wt=W1a-W1b and wb=W1b) + b1
    short8 th[4][2], tl[4][2], uh[4][2], ul[4][2];
    float bias1[4];
#pragma unroll
    for (int t = 0; t < 4; ++t) {
        bias1[t] = b1[t * 16 + n16];
#pragma unroll
        for (int ck = 0; ck < 2; ++ck) {
            short8 h1v, l1v, h2v, l2v;
#pragma unroll
            for (int j = 0; j < 8; ++j) {
                int d = ck * 32 + q * 8 + j;
                float wbv = w1[(64 + d) * 64 + t * 16 + n16];
                float wtv = w1[d * 64 + t * 16 + n16] - wbv;
                unsigned short x1 = f2bf(wtv);
                h1v[j] = (short)x1; l1v[j] = (short)f2bf(wtv - bf2f(x1));
                unsigned short x2 = f2bf(wbv);
                h2v[j] = (short)x2; l2v[j] = (short)f2bf(wbv - bf2f(x2));
            }
            th[t][ck] = h1v; tl[t][ck] = l1v;
            uh[t][ck] = h2v; ul[t][ck] = l2v;
        }
    }

    int nwaves = gridDim.x * 4;
    int wid = blockIdx.x * 4 + wv;
    for (int tile = wid; tile < ntiles; tile += nwaves) {
        int v0 = tile * 16;
        // GEMM1: h1 tile in C/D layout -> LDS
        const float4* a4 = (const float4*)(agg + (size_t)(v0 + n16) * 32);
        float4 A0 = a4[2 * q], A1 = a4[2 * q + 1];
        float a[8] = {A0.x, A0.y, A0.z, A0.w, A1.x, A1.y, A1.z, A1.w};
        short8 ah, al;
#pragma unroll
        for (int j = 0; j < 8; ++j) { short h, l; splitT(a[j], h, l); ah[j] = h; al[j] = l; }
#pragma unroll
        for (int t = 0; t < 4; ++t) {
            f32x4 acc = (f32x4){gbias[t], gbias[t], gbias[t], gbias[t]};
            acc = __builtin_amdgcn_mfma_f32_16x16x32_bf16(ah, gh[t], acc, 0, 0, 0);
            acc = __builtin_amdgcn_mfma_f32_16x16x32_bf16(al, gh[t], acc, 0, 0, 0);
            acc = __builtin_amdgcn_mfma_f32_16x16x32_bf16(ah, gl[t], acc, 0, 0, 0);
#pragma unroll
            for (int i = 0; i < 4; ++i)
                T[(q * 4 + i) * 66 + t * 16 + n16] = tanhf(acc[i]);
        }
        // (wave-private LDS region: lgkmcnt ordering suffices, no barrier)
        // GEMM2: read h1 row n16 in A layout (k = ck*32 + q*8 + j)
        float b[16];
#pragma unroll
        for (int j = 0; j < 8; ++j) {
            b[j]     = T[n16 * 66 + q * 8 + j];
            b[8 + j] = T[n16 * 66 + 32 + q * 8 + j];
        }
        short8 ah0, ah1, al0, al1;
#pragma unroll
        for (int j = 0; j < 8; ++j) {
            short h, l;
            splitT(b[j], h, l);      ah0[j] = h; al0[j] = l;
            splitT(b[8 + j], h, l);  ah1[j] = h; al1[j] = l;
        }
#pragma unroll
        for (int t = 0; t < 4; ++t) {
            f32x4 aa = (f32x4){bias1[t], bias1[t], bias1[t], bias1[t]};
            aa = __builtin_amdgcn_mfma_f32_16x16x32_bf16(ah0, th[t][0], aa, 0, 0, 0);
            aa = __builtin_amdgcn_mfma_f32_16x16x32_bf16(ah1, th[t][1], aa, 0, 0, 0);
            aa = __builtin_amdgcn_mfma_f32_16x16x32_bf16(al0, th[t][0], aa, 0, 0, 0);
            aa = __builtin_amdgcn_mfma_f32_16x16x32_bf16(al1, th[t][1], aa, 0, 0, 0);
            aa = __builtin_amdgcn_mfma_f32_16x16x32_bf16(ah0, tl[t][0], aa, 0, 0, 0);
            aa = __builtin_amdgcn_mfma_f32_16x16x32_bf16(ah1, tl[t][1], aa, 0, 0, 0);
            f32x4 bb = (f32x4){0.f, 0.f, 0.f, 0.f};
            bb = __builtin_amdgcn_mfma_f32_16x16x32_bf16(ah0, uh[t][0], bb, 0, 0, 0);
            bb = __builtin_amdgcn_mfma_f32_16x16x32_bf16(ah1, uh[t][1], bb, 0, 0, 0);
            bb = __builtin_amdgcn_mfma_f32_16x16x32_bf16(al0, uh[t][0], bb, 0, 0, 0);
            bb = __builtin_amdgcn_mfma_f32_16x16x32_bf16(al1, uh[t][1], bb, 0, 0, 0);
            bb = __builtin_amdgcn_mfma_f32_16x16x32_bf16(ah0, ul[t][0], bb, 0, 0, 0);
            bb = __builtin_amdgcn_mfma_f32_16x16x32_bf16(ah1, ul[t][1], bb, 0, 0, 0);
#pragma unroll
            for (int i = 0; i < 4; ++i) {
                size_t off = (size_t)(v0 + q * 4 + i) * 64 + t * 16 + n16;
                atab[off] = (_Float16)aa[i];
                btab[off] = (_Float16)bb[i];
            }
        }
    }
}

// persistent waves; fp16 MFMA (fp32 acc); fused GCN2 node matmul in epilogue;
// h2 stored fp16; no atomics.
// R1/R2: 2-stage node pipeline — next node's ptr pair / atab frags / first csr
// tile are prefetched while the current node computes, so the per-node critical
// path is only the btab gather. part[] reduction is a DPP rotate-add tree.
__global__ __launch_bounds__(256) void k_edge_mlp(
        const int* __restrict__ ptr, const int* __restrict__ csr_row,
        const _Float16* __restrict__ atab, const _Float16* __restrict__ btab,
        const float* __restrict__ w2, const float* __restrict__ b2,
        const float* __restrict__ wg, _Float16* __restrict__ h2h, int n) {
    int lane = threadIdx.x & 63;
    int n16 = lane & 15, q = lane >> 4;

    f16x8 wh[4][2];
    float bias[4];
    float wgf[4][4];    // Wg2 rows {t*16+n16}, cols {q*4+jj}
#pragma unroll
    for (int t = 0; t < 4; ++t) {
        bias[t] = b2[t * 16 + n16];
#pragma unroll
        for (int jj = 0; jj < 4; ++jj)
            wgf[t][jj] = wg[(t * 16 + n16) * 16 + q * 4 + jj];
#pragma unroll
        for (int ck = 0; ck < 2; ++ck) {
            f16x8 hh;
#pragma unroll
            for (int j = 0; j < 8; ++j)
                hh[j] = (_Float16)w2[(ck * 32 + q * 8 + j) * 64 + t * 16 + n16];
            wh[t][ck] = hh;
        }
    }

    int nwaves = gridDim.x * 4;
    int wid = blockIdx.x * 4 + (threadIdx.x >> 6);
    if (wid >= n) return;

    // ---- pipeline prologue: stage node `c` ----
    int c = wid;
    int st = ptr[c], ed = ptr[c + 1];
    const f16x8* a8 = (const f16x8*)(atab + (size_t)c * 64);
    f16x8 A0 = a8[q], A1 = a8[4 + q];
    int r0 = 0;
    if (st < ed) {                       // first-tile csr rows (clamped; masked later)
        int idx = st + n16;
        if (idx >= ed) idx = ed - 1;
        r0 = csr_row[idx];
    }

    while (true) {
        // ---- issue next node's independent loads FIRST (overlap with compute) ----
        int cn = c + nwaves;
        bool hasN = cn < n;
        int stn = 0, edn = 0;
        f16x8 B0, B1;
        if (hasN) {
            stn = ptr[cn]; edn = ptr[cn + 1];
            const f16x8* b8n = (const f16x8*)(atab + (size_t)cn * 64);
            B0 = b8n[q]; B1 = b8n[4 + q];
        }

        // ---- process node c (first csr tile already in r0) ----
        float red[4] = {0.f, 0.f, 0.f, 0.f};   // init 0 folds relu + empty-segment-0
        int p0 = st;
        int nfull = (ed - st) >> 4;
        int r = r0;
        for (int ft = 0; ft < nfull; ++ft, p0 += 16) {
            int rcur = r;
            int pn = p0 + 16 + n16;
            if (pn < ed) r = csr_row[pn];      // next full tile OR remainder rows
            const f16x8* b8 = (const f16x8*)(btab + (size_t)rcur * 64);
            f16x8 u0 = relu8(A0 + b8[q]);
            f16x8 u1 = relu8(A1 + b8[4 + q]);
#pragma unroll
            for (int t = 0; t < 4; ++t) {
                f32x4 acc = (f32x4){bias[t], bias[t], bias[t], bias[t]};
                acc = __builtin_amdgcn_mfma_f32_16x16x32_f16(u0, wh[t][0], acc, 0, 0, 0);
                acc = __builtin_amdgcn_mfma_f32_16x16x32_f16(u1, wh[t][1], acc, 0, 0, 0);
                red[t] = fmaxf(red[t], fmaxf(fmaxf(acc[0], acc[1]), fmaxf(acc[2], acc[3])));
            }
        }
        int rem = ed - p0;
        if (rem > 0) {
            f16x8 u0 = {0, 0, 0, 0, 0, 0, 0, 0};
            f16x8 u1 = {0, 0, 0, 0, 0, 0, 0, 0};
            if (n16 < rem) {
                const f16x8* b8 = (const f16x8*)(btab + (size_t)r * 64);
                u0 = relu8(A0 + b8[q]);
                u1 = relu8(A1 + b8[4 + q]);
            }
#pragma unroll
            for (int t = 0; t < 4; ++t) {
                f32x4 acc = (f32x4){bias[t], bias[t], bias[t], bias[t]};
                acc = __builtin_amdgcn_mfma_f32_16x16x32_f16(u0, wh[t][0], acc, 0, 0, 0);
                acc = __builtin_amdgcn_mfma_f32_16x16x32_f16(u1, wh[t][1], acc, 0, 0, 0);
#pragma unroll
                for (int i = 0; i < 4; ++i)
                    if (q * 4 + i < rem) red[t] = fmaxf(red[t], acc[i]);
            }
        }

        // ---- prefetch next node's first csr tile (stn/edn arrived by now) ----
        int r0n = 0;
        if (hasN && stn < edn) {
            int idx = stn + n16;
            if (idx >= edn) idx = edn - 1;
            r0n = csr_row[idx];
        }

        // ---- epilogue: segment-max across q (xor16/32, known-good shfl) ----
#pragma unroll
        for (int t = 0; t < 4; ++t) {
            red[t] = fmaxf(red[t], __shfl_xor(red[t], 16));
            red[t] = fmaxf(red[t], __shfl_xor(red[t], 32));
        }
        // fused GCN2 node matmul: h2[c][q*4+jj] = sum_d hmax[d]*wg[d][q*4+jj]
        float part[4];
#pragma unroll
        for (int jj = 0; jj < 4; ++jj) {
            part[jj] = red[0] * wgf[0][jj];
            part[jj] = fmaf(red[1], wgf[1][jj], part[jj]);
            part[jj] = fmaf(red[2], wgf[2][jj], part[jj]);
            part[jj] = fmaf(red[3], wgf[3][jj], part[jj]);
            // 16-lane rotate-add tree (full sum in every lane), DPP row_ror
            ROR_ADD(part[jj], 0x121);
            ROR_ADD(part[jj], 0x122);
            ROR_ADD(part[jj], 0x124);
            ROR_ADD(part[jj], 0x128);
        }
        if (n16 == 0) {
            f16x4 ph;
            ph[0] = (_Float16)part[0]; ph[1] = (_Float16)part[1];
            ph[2] = (_Float16)part[2]; ph[3] = (_Float16)part[3];
            ((f16x4*)(h2h + (size_t)c * 16))[q] = ph;
        }

        if (!hasN) break;
        // ---- rotate pipeline state ----
        c = cn; st = stn; ed = edn; A0 = B0; A1 = B1; r0 = r0n;
    }
}

// out[c] = bg + dv*(dv*h2[c] + sum_in dinv[r]*h2[r]) ; fully writes d_out
__global__ __launch_bounds__(256) void k_gcn2_gather(
        const int* __restrict__ ptr, const int* __restrict__ csr_row,
        const _Float16* __restrict__ h2h, const float* __restrict__ dinv,
        const float* __restrict__ bg, float* __restrict__ out, int n) {
    int wid = blockIdx.x * 4 + (threadIdx.x >> 6);
    if (wid >= n) return;
    int lane = threadIdx.x & 63;
    int f2 = lane & 7, slot = lane >> 3;
    int c = wid;
    int start = ptr[c], end = ptr[c + 1];
    const f16x2* h22 = (const f16x2*)h2h;
    float sx = 0.f, sy = 0.f;
    int p = start + slot;
    int r = (p < end) ? csr_row[p] : 0;
    while (p < end) {
        int rcur = r;
        int pn = p + 8;
        if (pn < end) r = csr_row[pn];
        float dr = dinv[rcur];
        f16x2 hv = h22[(size_t)rcur * 8 + f2];
        sx = fmaf(dr, (float)hv[0], sx);
        sy = fmaf(dr, (float)hv[1], sy);
        p = pn;
    }
    // xor-8 via DPP (pure VALU); xor-16/32 via shfl (known-good)
    ROR8_ADD(sx); ROR8_ADD(sy);
#pragma unroll
    for (int off = 16; off < 64; off <<= 1) {
        sx += __shfl_xor(sx, off);
        sy += __shfl_xor(sy, off);
    }
    if (slot == 0) {
        float dv = dinv[c];
        f16x2 hv = h22[(size_t)c * 8 + f2];
        float2 o;
        o.x = bg[2 * f2]     + dv * (dv * (float)hv[0] + sx);
        o.y = bg[2 * f2 + 1] + dv * (dv * (float)hv[1] + sy);
        ((float2*)out)[(size_t)c * 8 + f2] = o;
    }
}

extern "C" void kernel_launch(void* const* d_in, const int* in_sizes, int n_in,
                              void* d_out, int out_size, void* d_ws, size_t ws_size,
                              hipStream_t stream) {
    const float* x   = (const float*)d_in[0];
    const int*   ei  = (const int*)d_in[1];
    const float* g1w = (const float*)d_in[2];
    const float* g1b = (const float*)d_in[3];
    const float* ew1 = (const float*)d_in[4];
    const float* eb1 = (const float*)d_in[5];
    const float* ew2 = (const float*)d_in[6];
    const float* eb2 = (const float*)d_in[7];
    const float* g2w = (const float*)d_in[8];
    const float* g2b = (const float*)d_in[9];
    float* out = (float*)d_out;
    float* ws  = (float*)d_ws;

    const int n = in_sizes[0] / 32;      // 50000
    const int E = in_sizes[1] / 2;       // 800000
    const int* row = ei;
    const int* col = ei + E;
    const int ntiles = (n + 15) / 16;    // 3125
    const int nbuck = (n + 127) >> 7;    // 391 buckets of 128 cols

    size_t npad    = ((size_t)n + 63) & ~(size_t)63;
    size_t o_deg   = 0;
    size_t o_ptr   = npad;                      // n+1 (+pad)
    size_t o_csr   = o_ptr + npad + 64;         // E ints
    size_t o_dinv  = o_csr + (size_t)E;
    size_t o_atab  = o_dinv + npad;             // n*64 fp16 = n*32 floats
    size_t o_btab  = o_atab + (size_t)n * 32;   // n*64 fp16
    size_t o_agg   = o_btab + (size_t)n * 32;   // n*32 fp32
    size_t o_xh    = o_agg + (size_t)n * 32;    // n*32 fp16 = n*16 floats
    size_t o_h2h   = o_xh + (size_t)n * 16;     // n*16 fp16 = n*8 floats
    size_t o_stage = o_h2h + (size_t)n * 8;     // E int2 (8B aligned: offsets even)
    size_t o_bcur  = o_stage + (size_t)E * 2;   // nbuck ints
    size_t o_part  = o_bcur + 512;              // 64 ints

    int*      deg    = (int*)(ws + o_deg);
    int*      ptr    = (int*)(ws + o_ptr);
    int*      csr    = (int*)(ws + o_csr);
    float*    dinv   = ws + o_dinv;
    _Float16* atab   = (_Float16*)(ws + o_atab);
    _Float16* btab   = (_Float16*)(ws + o_btab);
    float*    agg    = ws + o_agg;
    _Float16* xh     = (_Float16*)(ws + o_xh);
    _Float16* h2h    = (_Float16*)(ws + o_h2h);
    int2*     stage  = (int2*)(ws + o_stage);
    int*      bcur   = (int*)(ws + o_bcur);
    int*      part   = (int*)(ws + o_part);

    int nblk = (n + 3) / 4;                      // wave-per-node kernels, 4 waves/block
    int scan_nb = (n + SCAN_CHUNK - 1) / SCAN_CHUNK;   // 25 <= 64
    int fill_nb = (E + FILL_CH - 1) / FILL_CH;         // 196
    int m4 = n * 8;                                    // x float4 count

    hipMemsetAsync(deg, 0, npad * sizeof(int), stream);
    k_deg_cast<<<(E + 255) / 256, 256, 0, stream>>>(col, deg, (const float4*)x,
                                                    (f16x4*)xh, E, m4);
    k_scan_partial<<<scan_nb, 256, 0, stream>>>(deg, part, n);
    k_scan_final<<<scan_nb, 256, 0, stream>>>(deg, part, ptr, bcur, dinv, n, scan_nb, E);
    k_fill_a<<<fill_nb, 256, 0, stream>>>(row, col, bcur, stage, E, nbuck);
    k_fill_b<<<nbuck, 256, 0, stream>>>(ptr, stage, csr, n);
    k_gather32<<<nblk, 256, 0, stream>>>(ptr, csr, x, xh, dinv, agg, n);
    k_h1tab<<<256, 256, 0, stream>>>(agg, g1w, g1b, ew1, eb1, atab, btab, ntiles);
    k_edge_mlp<<<2048, 256, 0, stream>>>(ptr, csr, atab, btab, ew2, eb2, g2w, h2h, n);
    k_gcn2_gather<<<nblk, 256, 0, stream>>>(ptr, csr, h2h, dinv, g2b, out, n);
}

// Round 3
// 200.887 us; speedup vs baseline: 1.1689x; 1.1689x over previous
//
#include <hip/hip_runtime.h>

// CSR-gather pipeline (no float atomics):
//   memset(bcnt) ; cast_count (x->fp16 + bucket hist) ; bucket_scan (1 blk) ;
//   fill_a ; fill_b2 (per-bucket node hist + scan + ptr/dinv/csr) ; gather32 ;
//   h1tab ; edge_mlp (R0 structure, DPP epilogue) ; gcn2_gather
// R3: build phase restructured — per-node deg array + 2 scan kernels removed;
//     per-node ptr/dinv derived inside the bucket kernel. edge_mlp reverted to
//     R0 loop (60 VGPR / best measured) keeping the DPP part[] tree from R2.

typedef __attribute__((ext_vector_type(8))) short short8;
typedef __attribute__((ext_vector_type(4))) float f32x4;
typedef __attribute__((ext_vector_type(8))) _Float16 f16x8;
typedef __attribute__((ext_vector_type(4))) _Float16 f16x4;
typedef __attribute__((ext_vector_type(2))) _Float16 f16x2;

#define FILL_CH 4096      // edges per phase-A block (256 thr x 16)

__device__ __forceinline__ unsigned short f2bf(float x) {   // RNE f32->bf16 (cold paths only)
    unsigned int u = __float_as_uint(x);
    return (unsigned short)((u + 0x7FFFu + ((u >> 16) & 1u)) >> 16);
}
__device__ __forceinline__ float bf2f(unsigned short h) {
    return __uint_as_float(((unsigned int)h) << 16);
}
// cheap truncation split: u ~= hi + lo with |err| ~ 2^-16 |u|
__device__ __forceinline__ void splitT(float u, short& hi, short& lo) {
    unsigned int ub = __float_as_uint(u);
    hi = (short)(ub >> 16);
    float r = u - __uint_as_float(ub & 0xFFFF0000u);
    lo = (short)(__float_as_uint(r) >> 16);
}
__device__ __forceinline__ f16x8 relu8(f16x8 v) {
    f16x8 z = {0, 0, 0, 0, 0, 0, 0, 0};
#if __has_builtin(__builtin_elementwise_max)
    return __builtin_elementwise_max(v, z);
#else
    f16x8 o;
#pragma unroll
    for (int j = 0; j < 8; ++j) o[j] = v[j] > (_Float16)0 ? v[j] : (_Float16)0;
    return o;
#endif
}

// rotate-add within a 16-lane row (DPP row_ror:N); rotation tree 1,2,4,8 == full
// 16-lane sum in every lane. Pure VALU, no lgkm wait. (row_ror = 0x120+N.)
#define ROR_ADD(s, CTRL)                                                         \
    s += __int_as_float(__builtin_amdgcn_update_dpp(                             \
        0, __float_as_int(s), (CTRL), 0xf, 0xf, false))
// xor-8 within a 16-lane row is row_ror:8 (flips bit 3 only)
#define ROR8_ADD(s) ROR_ADD(s, 0x128)

// fused: x -> fp16 cast + bucket-level edge histogram (LDS-aggregated)
__global__ __launch_bounds__(256) void k_cast_count(
        const int* __restrict__ col, const float4* __restrict__ x4,
        f16x4* __restrict__ xh4, int* __restrict__ bcnt, int E, int m4, int nb) {
    __shared__ int cnt[512];
    int tid = threadIdx.x;
    for (int i = tid; i < nb; i += 256) cnt[i] = 0;
    __syncthreads();
    int e0 = blockIdx.x * FILL_CH;
#pragma unroll
    for (int i = 0; i < 16; ++i) {
        int e = e0 + tid + i * 256;
        if (e < E) atomicAdd(&cnt[col[e] >> 7], 1);
    }
    // grid-stride cast (independent of the hist work)
    int nth = gridDim.x * 256;
    for (int idx = blockIdx.x * 256 + tid; idx < m4; idx += nth) {
        float4 v = x4[idx];
        f16x4 o;
        o[0] = (_Float16)v.x; o[1] = (_Float16)v.y;
        o[2] = (_Float16)v.z; o[3] = (_Float16)v.w;
        xh4[idx] = o;
    }
    __syncthreads();
    for (int i = tid; i < nb; i += 256)
        if (cnt[i]) atomicAdd(&bcnt[i], cnt[i]);
}

// single block: exclusive scan of nb (<=512) bucket counts -> bbase, bcur
__global__ __launch_bounds__(512) void k_bucket_scan(
        const int* __restrict__ bcnt, int* __restrict__ bbase,
        int* __restrict__ bcur, int* __restrict__ ptr, int nb, int n, int E) {
    __shared__ int wt[8];
    int tid = threadIdx.x;
    int lane = tid & 63, w = tid >> 6;
    int v = (tid < nb) ? bcnt[tid] : 0;
    int s = v;
    for (int off = 1; off < 64; off <<= 1) {
        int t = __shfl_up(s, off, 64);
        if (lane >= off) s += t;
    }
    if (lane == 63) wt[w] = s;
    __syncthreads();
    int pre = 0;
    for (int i = 0; i < 8; ++i) if (i < w) pre += wt[i];
    int excl = pre + s - v;
    if (tid < nb) { bbase[tid] = excl; bcur[tid] = excl; }
    if (tid == nb) bbase[tid] = E;
    if (tid == 0) ptr[n] = E;
}

// fill phase A: bucket edges (128 cols/bucket) into contiguous per-bucket runs
__global__ __launch_bounds__(256) void k_fill_a(const int* __restrict__ row,
                                                const int* __restrict__ col,
                                                int* __restrict__ bcur,
                                                int2* __restrict__ stage, int E, int nb) {
    __shared__ int cnt[512];
    __shared__ int base[512];
    int tid = threadIdx.x;
    int e0 = blockIdx.x * FILL_CH;
    for (int i = tid; i < nb; i += 256) cnt[i] = 0;
    __syncthreads();
    int r[16], c[16];
#pragma unroll
    for (int i = 0; i < 16; ++i) {
        int e = e0 + tid + i * 256;
        if (e < E) {
            r[i] = row[e]; c[i] = col[e];
            atomicAdd(&cnt[c[i] >> 7], 1);
        } else c[i] = -1;
    }
    __syncthreads();
    for (int i = tid; i < nb; i += 256)
        base[i] = cnt[i] ? atomicAdd(&bcur[i], cnt[i]) : 0;
    __syncthreads();
    for (int i = tid; i < nb; i += 256) cnt[i] = 0;
    __syncthreads();
#pragma unroll
    for (int i = 0; i < 16; ++i) {
        if (c[i] >= 0) {
            int b = c[i] >> 7;
            int lp = atomicAdd(&cnt[b], 1);
            stage[base[b] + lp] = make_int2(r[i], c[i]);
        }
    }
}

// fill phase B2: one block per bucket; local 128-col hist + exclusive scan
// produces ptr/dinv for this bucket's nodes, then scatters csr via LDS cursors.
__global__ __launch_bounds__(256) void k_fill_b2(
        const int* __restrict__ bbase, const int* __restrict__ bcur_end,
        const int2* __restrict__ stage, int* __restrict__ ptr,
        float* __restrict__ dinv, int* __restrict__ csr, int n) {
    __shared__ int lcnt[128];
    __shared__ int lcur[128];
    __shared__ int wtotS;
    int b = blockIdx.x, tid = threadIdx.x;
    int c0 = b << 7;
    int start = bbase[b], end = bcur_end[b];   // bcur after fill_a == base+count
    if (tid < 128) lcnt[tid] = 0;
    __syncthreads();
    for (int p = start + tid; p < end; p += 256)
        atomicAdd(&lcnt[stage[p].y & 127], 1);
    __syncthreads();
    // exclusive scan of 128 counts (waves 0/1 carry real data)
    int lane = tid & 63, w = tid >> 6;
    int v = (tid < 128) ? lcnt[tid] : 0;
    int s = v;
    for (int off = 1; off < 64; off <<= 1) {
        int t = __shfl_up(s, off, 64);
        if (lane >= off) s += t;
    }
    if (tid == 63) wtotS = s;          // wave0 inclusive total
    __syncthreads();
    int excl = s - v + ((w == 1) ? wtotS : 0);
    if (tid < 128) {
        int c = c0 + tid;
        int basep = start + excl;
        lcur[tid] = basep;
        if (c < n) {
            ptr[c] = basep;
            dinv[c] = rsqrtf((float)(v + 1));   // +1 self loop
        }
    }
    __syncthreads();
    for (int p = start + tid; p < end; p += 256) {
        int2 rc = stage[p];
        int pos = atomicAdd(&lcur[rc.y & 127], 1);
        csr[pos] = rc.x;
    }
}

// irregular gather (fp16 x): agg[v] = dv*(sum dinv[r]*xh[r]) + dv^2*x[v]
// 8 edge slots x 8 lanes x half4; one-ahead index prefetch; fp32 accumulate
__global__ __launch_bounds__(256) void k_gather32(
        const int* __restrict__ ptr, const int* __restrict__ csr_row,
        const float* __restrict__ x, const _Float16* __restrict__ xh,
        const float* __restrict__ dinv, float* __restrict__ agg, int n) {
    int wid = blockIdx.x * 4 + (threadIdx.x >> 6);
    if (wid >= n) return;
    int lane = threadIdx.x & 63;
    int f4 = lane & 7, slot = lane >> 3;
    int v = wid;
    int start = ptr[v], end = ptr[v + 1];
    const f16x4* xh4 = (const f16x4*)xh;
    float sx = 0.f, sy = 0.f, sz = 0.f, sw = 0.f;
    int p = start + slot;
    int r = (p < end) ? csr_row[p] : 0;
    while (p < end) {
        int rcur = r;
        int pn = p + 8;
        if (pn < end) r = csr_row[pn];
        float dr = dinv[rcur];
        f16x4 xv = xh4[(size_t)rcur * 8 + f4];
        sx = fmaf(dr, (float)xv[0], sx);
        sy = fmaf(dr, (float)xv[1], sy);
        sz = fmaf(dr, (float)xv[2], sz);
        sw = fmaf(dr, (float)xv[3], sw);
        p = pn;
    }
    // xor-8 via DPP (pure VALU); xor-16/32 via shfl (known-good)
    ROR8_ADD(sx); ROR8_ADD(sy); ROR8_ADD(sz); ROR8_ADD(sw);
#pragma unroll
    for (int off = 16; off < 64; off <<= 1) {
        sx += __shfl_xor(sx, off); sy += __shfl_xor(sy, off);
        sz += __shfl_xor(sz, off); sw += __shfl_xor(sw, off);
    }
    if (slot == 0) {
        float dv = dinv[v], d2 = dv * dv;
        float4 xv = ((const float4*)x)[(size_t)v * 8 + f4];   // self term fp32
        float4 o;
        o.x = dv * sx + d2 * xv.x;
        o.y = dv * sy + d2 * xv.y;
        o.z = dv * sz + d2 * xv.z;
        o.w = dv * sw + d2 * xv.w;
        ((float4*)agg)[(size_t)v * 8 + f4] = o;
    }
}

// FUSED dense MFMA: h1 = tanh(agg @ Wg1 + gb)  then  atab = h1@(W1a-W1b)+b1 ;
// btab = h1@W1b (fp16 out). h1 never leaves the CU: C/D -> A layout transform
// via wave-private LDS tile (16 x 66, pad keeps <=2-way bank aliasing).
__global__ __launch_bounds__(256, 1) void k_h1tab(
        const float* __restrict__ agg, const float* __restrict__ gw,
        const float* __restrict__ gb, const float* __restrict__ w1,
        const float* __restrict__ b1,
        _Float16* __restrict__ atab, _Float16* __restrict__ btab, int ntiles) {
    __shared__ float tileS[4][16 * 66];
    int lane = threadIdx.x & 63;
    int wv = threadIdx.x >> 6;
    int n16 = lane & 15, q = lane >> 4;
    float* T = tileS[wv];

    // Wg1 frags (bf16 3-term) + gb
    short8 gh[4], gl[4];
    float gbias[4];
#pragma unroll
    for (int t = 0; t < 4; ++t) {
        gbias[t] = gb[t * 16 + n16];
        short8 hh, ll;
#pragma unroll
        for (int j = 0; j < 8; ++j) {
            float w = gw[(q * 8 + j) * 64 + t * 16 + n16];
            unsigned short wh = f2bf(w);
            hh[j] = (short)wh;
            ll[j] = (short)f2bf(w - bf2f(wh));
        }
        gh[t] = hh; gl[t] = ll;
    }
    // W1 frags (bf16 3-term, wt=W1a-W1b and wb=W1b) + b1
    short8 th[4][2], tl[4][2], uh[4][2], ul[4][2];
    float bias1[4];
#pragma unroll
    for (int t = 0; t < 4; ++t) {
        bias1[t] = b1[t * 16 + n16];
#pragma unroll
        for (int ck = 0; ck < 2; ++ck) {
            short8 h1v, l1v, h2v, l2v;
#pragma unroll
            for (int j = 0; j < 8; ++j) {
                int d = ck * 32 + q * 8 + j;
                float wbv = w1[(64 + d) * 64 + t * 16 + n16];
                float wtv = w1[d * 64 + t * 16 + n16] - wbv;
                unsigned short x1 = f2bf(wtv);
                h1v[j] = (short)x1; l1v[j] = (short)f2bf(wtv - bf2f(x1));
                unsigned short x2 = f2bf(wbv);
                h2v[j] = (short)x2; l2v[j] = (short)f2bf(wbv - bf2f(x2));
            }
            th[t][ck] = h1v; tl[t][ck] = l1v;
            uh[t][ck] = h2v; ul[t][ck] = l2v;
        }
    }

    int nwaves = gridDim.x * 4;
    int wid = blockIdx.x * 4 + wv;
    for (int tile = wid; tile < ntiles; tile += nwaves) {
        int v0 = tile * 16;
        // GEMM1: h1 tile in C/D layout -> LDS
        const float4* a4 = (const float4*)(agg + (size_t)(v0 + n16) * 32);
        float4 A0 = a4[2 * q], A1 = a4[2 * q + 1];
        float a[8] = {A0.x, A0.y, A0.z, A0.w, A1.x, A1.y, A1.z, A1.w};
        short8 ah, al;
#pragma unroll
        for (int j = 0; j < 8; ++j) { short h, l; splitT(a[j], h, l); ah[j] = h; al[j] = l; }
#pragma unroll
        for (int t = 0; t < 4; ++t) {
            f32x4 acc = (f32x4){gbias[t], gbias[t], gbias[t], gbias[t]};
            acc = __builtin_amdgcn_mfma_f32_16x16x32_bf16(ah, gh[t], acc, 0, 0, 0);
            acc = __builtin_amdgcn_mfma_f32_16x16x32_bf16(al, gh[t], acc, 0, 0, 0);
            acc = __builtin_amdgcn_mfma_f32_16x16x32_bf16(ah, gl[t], acc, 0, 0, 0);
#pragma unroll
            for (int i = 0; i < 4; ++i)
                T[(q * 4 + i) * 66 + t * 16 + n16] = tanhf(acc[i]);
        }
        // (wave-private LDS region: lgkmcnt ordering suffices, no barrier)
        // GEMM2: read h1 row n16 in A layout (k = ck*32 + q*8 + j)
        float b[16];
#pragma unroll
        for (int j = 0; j < 8; ++j) {
            b[j]     = T[n16 * 66 + q * 8 + j];
            b[8 + j] = T[n16 * 66 + 32 + q * 8 + j];
        }
        short8 ah0, ah1, al0, al1;
#pragma unroll
        for (int j = 0; j < 8; ++j) {
            short h, l;
            splitT(b[j], h, l);      ah0[j] = h; al0[j] = l;
            splitT(b[8 + j], h, l);  ah1[j] = h; al1[j] = l;
        }
#pragma unroll
        for (int t = 0; t < 4; ++t) {
            f32x4 aa = (f32x4){bias1[t], bias1[t], bias1[t], bias1[t]};
            aa = __builtin_amdgcn_mfma_f32_16x16x32_bf16(ah0, th[t][0], aa, 0, 0, 0);
            aa = __builtin_amdgcn_mfma_f32_16x16x32_bf16(ah1, th[t][1], aa, 0, 0, 0);
            aa = __builtin_amdgcn_mfma_f32_16x16x32_bf16(al0, th[t][0], aa, 0, 0, 0);
            aa = __builtin_amdgcn_mfma_f32_16x16x32_bf16(al1, th[t][1], aa, 0, 0, 0);
            aa = __builtin_amdgcn_mfma_f32_16x16x32_bf16(ah0, tl[t][0], aa, 0, 0, 0);
            aa = __builtin_amdgcn_mfma_f32_16x16x32_bf16(ah1, tl[t][1], aa, 0, 0, 0);
            f32x4 bb = (f32x4){0.f, 0.f, 0.f, 0.f};
            bb = __builtin_amdgcn_mfma_f32_16x16x32_bf16(ah0, uh[t][0], bb, 0, 0, 0);
            bb = __builtin_amdgcn_mfma_f32_16x16x32_bf16(ah1, uh[t][1], bb, 0, 0, 0);
            bb = __builtin_amdgcn_mfma_f32_16x16x32_bf16(al0, uh[t][0], bb, 0, 0, 0);
            bb = __builtin_amdgcn_mfma_f32_16x16x32_bf16(al1, uh[t][1], bb, 0, 0, 0);
            bb = __builtin_amdgcn_mfma_f32_16x16x32_bf16(ah0, ul[t][0], bb, 0, 0, 0);
            bb = __builtin_amdgcn_mfma_f32_16x16x32_bf16(ah1, ul[t][1], bb, 0, 0, 0);
#pragma unroll
            for (int i = 0; i < 4; ++i) {
                size_t off = (size_t)(v0 + q * 4 + i) * 64 + t * 16 + n16;
                atab[off] = (_Float16)aa[i];
                btab[off] = (_Float16)bb[i];
            }
        }
    }
}

// persistent waves; R0 structure (best measured: 60 VGPR, simple tile loop);
// fp16 MFMA (fp32 acc); fused GCN2 node matmul in epilogue; h2 stored fp16.
__global__ __launch_bounds__(256) void k_edge_mlp(
        const int* __restrict__ ptr, const int* __restrict__ csr_row,
        const _Float16* __restrict__ atab, const _Float16* __restrict__ btab,
        const float* __restrict__ w2, const float* __restrict__ b2,
        const float* __restrict__ wg, _Float16* __restrict__ h2h, int n) {
    int lane = threadIdx.x & 63;
    int n16 = lane & 15, q = lane >> 4;

    f16x8 wh[4][2];
    float bias[4];
    float wgf[4][4];    // Wg2 rows {t*16+n16}, cols {q*4+jj}
#pragma unroll
    for (int t = 0; t < 4; ++t) {
        bias[t] = b2[t * 16 + n16];
#pragma unroll
        for (int jj = 0; jj < 4; ++jj)
            wgf[t][jj] = wg[(t * 16 + n16) * 16 + q * 4 + jj];
#pragma unroll
        for (int ck = 0; ck < 2; ++ck) {
            f16x8 hh;
#pragma unroll
            for (int j = 0; j < 8; ++j)
                hh[j] = (_Float16)w2[(ck * 32 + q * 8 + j) * 64 + t * 16 + n16];
            wh[t][ck] = hh;
        }
    }

    int nwaves = gridDim.x * 4;
    int wid = blockIdx.x * 4 + (threadIdx.x >> 6);

    for (int c = wid; c < n; c += nwaves) {
        int st = ptr[c], ed = ptr[c + 1];
        const f16x8* a8 = (const f16x8*)(atab + (size_t)c * 64);
        f16x8 A0 = a8[q], A1 = a8[4 + q];
        float red[4] = {0.f, 0.f, 0.f, 0.f};   // init 0 folds relu + empty-segment-0

        int p0 = st;
        int nfull = (ed - st) >> 4;
        for (int ft = 0; ft < nfull; ++ft, p0 += 16) {
            int r = csr_row[p0 + n16];
            const f16x8* b8 = (const f16x8*)(btab + (size_t)r * 64);
            f16x8 u0 = relu8(A0 + b8[q]);
            f16x8 u1 = relu8(A1 + b8[4 + q]);
#pragma unroll
            for (int t = 0; t < 4; ++t) {
                f32x4 acc = (f32x4){bias[t], bias[t], bias[t], bias[t]};
                acc = __builtin_amdgcn_mfma_f32_16x16x32_f16(u0, wh[t][0], acc, 0, 0, 0);
                acc = __builtin_amdgcn_mfma_f32_16x16x32_f16(u1, wh[t][1], acc, 0, 0, 0);
                red[t] = fmaxf(red[t], fmaxf(fmaxf(acc[0], acc[1]), fmaxf(acc[2], acc[3])));
            }
        }
        int rem = ed - p0;
        if (rem > 0) {
            f16x8 u0 = {0, 0, 0, 0, 0, 0, 0, 0};
            f16x8 u1 = {0, 0, 0, 0, 0, 0, 0, 0};
            if (n16 < rem) {
                int r = csr_row[p0 + n16];
                const f16x8* b8 = (const f16x8*)(btab + (size_t)r * 64);
                u0 = relu8(A0 + b8[q]);
                u1 = relu8(A1 + b8[4 + q]);
            }
#pragma unroll
            for (int t = 0; t < 4; ++t) {
                f32x4 acc = (f32x4){bias[t], bias[t], bias[t], bias[t]};
                acc = __builtin_amdgcn_mfma_f32_16x16x32_f16(u0, wh[t][0], acc, 0, 0, 0);
                acc = __builtin_amdgcn_mfma_f32_16x16x32_f16(u1, wh[t][1], acc, 0, 0, 0);
#pragma unroll
                for (int i = 0; i < 4; ++i)
                    if (q * 4 + i < rem) red[t] = fmaxf(red[t], acc[i]);
            }
        }
        // butterfly: all lanes get final segment-max for features t*16+n16
#pragma unroll
        for (int t = 0; t < 4; ++t) {
            red[t] = fmaxf(red[t], __shfl_xor(red[t], 16));
            red[t] = fmaxf(red[t], __shfl_xor(red[t], 32));
        }
        // fused GCN2 node matmul: h2[c][q*4+jj] = sum_d hmax[d]*wg[d][q*4+jj]
        float part[4];
#pragma unroll
        for (int jj = 0; jj < 4; ++jj) {
            part[jj] = red[0] * wgf[0][jj];
            part[jj] = fmaf(red[1], wgf[1][jj], part[jj]);
            part[jj] = fmaf(red[2], wgf[2][jj], part[jj]);
            part[jj] = fmaf(red[3], wgf[3][jj], part[jj]);
            // 16-lane rotate-add tree (full sum in every lane), DPP row_ror
            ROR_ADD(part[jj], 0x121);
            ROR_ADD(part[jj], 0x122);
            ROR_ADD(part[jj], 0x124);
            ROR_ADD(part[jj], 0x128);
        }
        if (n16 == 0) {
            f16x4 ph;
            ph[0] = (_Float16)part[0]; ph[1] = (_Float16)part[1];
            ph[2] = (_Float16)part[2]; ph[3] = (_Float16)part[3];
            ((f16x4*)(h2h + (size_t)c * 16))[q] = ph;
        }
    }
}

// out[c] = bg + dv*(dv*h2[c] + sum_in dinv[r]*h2[r]) ; fully writes d_out
__global__ __launch_bounds__(256) void k_gcn2_gather(
        const int* __restrict__ ptr, const int* __restrict__ csr_row,
        const _Float16* __restrict__ h2h, const float* __restrict__ dinv,
        const float* __restrict__ bg, float* __restrict__ out, int n) {
    int wid = blockIdx.x * 4 + (threadIdx.x >> 6);
    if (wid >= n) return;
    int lane = threadIdx.x & 63;
    int f2 = lane & 7, slot = lane >> 3;
    int c = wid;
    int start = ptr[c], end = ptr[c + 1];
    const f16x2* h22 = (const f16x2*)h2h;
    float sx = 0.f, sy = 0.f;
    int p = start + slot;
    int r = (p < end) ? csr_row[p] : 0;
    while (p < end) {
        int rcur = r;
        int pn = p + 8;
        if (pn < end) r = csr_row[pn];
        float dr = dinv[rcur];
        f16x2 hv = h22[(size_t)rcur * 8 + f2];
        sx = fmaf(dr, (float)hv[0], sx);
        sy = fmaf(dr, (float)hv[1], sy);
        p = pn;
    }
    // xor-8 via DPP (pure VALU); xor-16/32 via shfl (known-good)
    ROR8_ADD(sx); ROR8_ADD(sy);
#pragma unroll
    for (int off = 16; off < 64; off <<= 1) {
        sx += __shfl_xor(sx, off);
        sy += __shfl_xor(sy, off);
    }
    if (slot == 0) {
        float dv = dinv[c];
        f16x2 hv = h22[(size_t)c * 8 + f2];
        float2 o;
        o.x = bg[2 * f2]     + dv * (dv * (float)hv[0] + sx);
        o.y = bg[2 * f2 + 1] + dv * (dv * (float)hv[1] + sy);
        ((float2*)out)[(size_t)c * 8 + f2] = o;
    }
}

extern "C" void kernel_launch(void* const* d_in, const int* in_sizes, int n_in,
                              void* d_out, int out_size, void* d_ws, size_t ws_size,
                              hipStream_t stream) {
    const float* x   = (const float*)d_in[0];
    const int*   ei  = (const int*)d_in[1];
    const float* g1w = (const float*)d_in[2];
    const float* g1b = (const float*)d_in[3];
    const float* ew1 = (const float*)d_in[4];
    const float* eb1 = (const float*)d_in[5];
    const float* ew2 = (const float*)d_in[6];
    const float* eb2 = (const float*)d_in[7];
    const float* g2w = (const float*)d_in[8];
    const float* g2b = (const float*)d_in[9];
    float* out = (float*)d_out;
    float* ws  = (float*)d_ws;

    const int n = in_sizes[0] / 32;      // 50000
    const int E = in_sizes[1] / 2;       // 800000
    const int* row = ei;
    const int* col = ei + E;
    const int ntiles = (n + 15) / 16;    // 3125
    const int nbuck = (n + 127) >> 7;    // 391 buckets of 128 cols

    size_t npad    = ((size_t)n + 63) & ~(size_t)63;
    size_t o_misc  = 0;                         // bcnt[512] + bbase[512] (ints)
    size_t o_ptr   = npad;                      // n+1 (+pad)
    size_t o_csr   = o_ptr + npad + 64;         // E ints
    size_t o_dinv  = o_csr + (size_t)E;
    size_t o_atab  = o_dinv + npad;             // n*64 fp16 = n*32 floats
    size_t o_btab  = o_atab + (size_t)n * 32;   // n*64 fp16
    size_t o_agg   = o_btab + (size_t)n * 32;   // n*32 fp32
    size_t o_xh    = o_agg + (size_t)n * 32;    // n*32 fp16 = n*16 floats
    size_t o_h2h   = o_xh + (size_t)n * 16;     // n*16 fp16 = n*8 floats
    size_t o_stage = o_h2h + (size_t)n * 8;     // E int2 (8B aligned: offsets even)
    size_t o_bcur  = o_stage + (size_t)E * 2;   // nbuck ints

    int*      bcnt   = (int*)(ws + o_misc);
    int*      bbase  = (int*)(ws + o_misc) + 512;
    int*      ptr    = (int*)(ws + o_ptr);
    int*      csr    = (int*)(ws + o_csr);
    float*    dinv   = ws + o_dinv;
    _Float16* atab   = (_Float16*)(ws + o_atab);
    _Float16* btab   = (_Float16*)(ws + o_btab);
    float*    agg    = ws + o_agg;
    _Float16* xh     = (_Float16*)(ws + o_xh);
    _Float16* h2h    = (_Float16*)(ws + o_h2h);
    int2*     stage  = (int2*)(ws + o_stage);
    int*      bcur   = (int*)(ws + o_bcur);

    int nblk = (n + 3) / 4;                      // wave-per-node kernels, 4 waves/block
    int fill_nb = (E + FILL_CH - 1) / FILL_CH;   // 196
    int m4 = n * 8;                              // x float4 count

    hipMemsetAsync(bcnt, 0, 512 * sizeof(int), stream);
    k_cast_count<<<fill_nb, 256, 0, stream>>>(col, (const float4*)x, (f16x4*)xh,
                                              bcnt, E, m4, nbuck);
    k_bucket_scan<<<1, 512, 0, stream>>>(bcnt, bbase, bcur, ptr, nbuck, n, E);
    k_fill_a<<<fill_nb, 256, 0, stream>>>(row, col, bcur, stage, E, nbuck);
    k_fill_b2<<<nbuck, 256, 0, stream>>>(bbase, bcur, stage, ptr, dinv, csr, n);
    k_gather32<<<nblk, 256, 0, stream>>>(ptr, csr, x, xh, dinv, agg, n);
    k_h1tab<<<256, 256, 0, stream>>>(agg, g1w, g1b, ew1, eb1, atab, btab, ntiles);
    k_edge_mlp<<<2048, 256, 0, stream>>>(ptr, csr, atab, btab, ew2, eb2, g2w, h2h, n);
    k_gcn2_gather<<<nblk, 256, 0, stream>>>(ptr, csr, h2h, dinv, g2b, out, n);
}